// Round 6
// baseline (876.228 us; speedup 1.0000x reference)
//
#include <hip/hip_runtime.h>

// ---------------------------------------------------------------------------
// SAGE 3-layer GNN — single persistent kernel with software grid barriers.
//   Per layer: S = X@W_self + b (fp32) ; P = X@W_neigh (bf16 row-major)
//              h[i] = act( S[i] + (sum_{j in N_in(i)} P[j]) / max(deg_i,1) )
//
// Evidence log:
//   R0..R5: global random row-gather agg ~150us. Wall = per-CU random-gather
//     service rate (~274 cyc/edge/CU), not bytes (R7 bf16 neutral).
//   R8 FAILED: dim-sliced LDS planes multiplied edge visits x32.
//   R9 WIN: src-bucket LDS slicing (bucket P-slice in LDS, CSR keyed
//     dst*NSB+bucket, wave-per-row LDS gather, coalesced 256B Hn atomics).
//   R10 WIN: finish 130us->off-list (sorted graph_id, per-wave register acc,
//     one coalesced flush per graph-change).
//   R11 WIN: CSR build 3 kernels -> 1 (fixed-capacity slot rows). 255.9us.
//     Top-5 = harness 268MB re-poison fill only (43us); ours all <41us.
//     Accounting: ~100us of remaining 213 = dispatch serialization.
//   R12 FAILED (container died, no profile): hipLaunchCooperativeKernel.
//     Hypothesis: cooperative launch rejected under graph capture AND
//     poisons capture state -> fallback also fails. Remove the API.
//   R13 (this round): same fusion via SOFTWARE grid barrier (sense-reversal,
//     device-scope atomics + __threadfence, G16 pattern), plain launch.
//     Co-residency made robust: NSB=16 buckets x 625 rows -> 80KB LDS/block,
//     __launch_bounds__(1024,8) -> 2 blocks/CU capacity; grid=256 resident
//     on >=128 CUs (huge margin vs 1/CU knife-edge). 12 dispatches -> 2
//     (tiny memset for barrier/cnt region + mega kernel, 7 barriers).
//   Predicted: total 255.9 -> ~150-190us; mega visible ~110-140us.
//   Contingency: if container fails again -> infra/spin-hostility; revert R11.
// ---------------------------------------------------------------------------

#define DH 64
#define NG 16
#define NSB 16       // src buckets
#define DTILES 16    // dst tiles -> 16*16 = 256 blocks
#define MAXNPB 625   // nodes per bucket (M <= 10000)
#define CAP 32       // edge slots per (dst,bucket) row; Poisson(2) tail ~4e-17
#define MEGA_BLOCKS 256
#define MEGA_THREADS 1024
#define NW_FIN 640   // finish-phase active waves (R10-proven contention)

__device__ __forceinline__ unsigned short f2bf(float f) {
    unsigned int u = __float_as_uint(f);
    unsigned int r = (u + 0x7FFFu + ((u >> 16) & 1u)) >> 16;   // RNE
    return (unsigned short)r;
}
__device__ __forceinline__ float bfu(unsigned short v) {
    return __uint_as_float(((unsigned int)v) << 16);
}
__device__ __forceinline__ int degN(const int* __restrict__ cnt, int n) {
    const int4* cp = reinterpret_cast<const int4*>(&cnt[n * NSB]);
    int4 c0 = cp[0], c1 = cp[1], c2 = cp[2], c3 = cp[3];
    return c0.x + c0.y + c0.z + c0.w + c1.x + c1.y + c1.z + c1.w +
           c2.x + c2.y + c2.z + c2.w + c3.x + c3.y + c3.z + c3.w;
}

struct MegaArgs {
    const float* feat; const int* src; const int* dst; const int* graph_id;
    const float* Ws1; const float* Wn1; const float* b1;
    const float* Ws2; const float* Wn2; const float* b2;
    const float* Ws3; const float* Wn3; const float* b3;
    const float* Wc; const float* bc;
    int* cnt16; int* es; int* bar;      // bar[0]=arrive count, bar[1]=generation
    float* S; unsigned short* P; float* Hn;
    float* out; float* out_feat; float* H;
    float* gsum; float* gcnt;
    int M, E, npb;
};

// ---- software grid barrier (sense-reversal via generation counter) --------
// Requires all gridDim.x blocks resident (guaranteed: 2 blocks/CU capacity,
// grid=256 <= 2*256). Device-scope atomics; __threadfence() = agent-scope
// fence (L2 writeback/invalidate across XCDs per G16).
__device__ __forceinline__ void grid_sync(int* cnt, int* gen, int nb) {
    __syncthreads();                        // block writes drained (vmcnt 0)
    if (threadIdx.x == 0) {
        __threadfence();                    // release: publish this XCD's L2
        int g = __hip_atomic_load(gen, __ATOMIC_RELAXED, __HIP_MEMORY_SCOPE_AGENT);
        int a = __hip_atomic_fetch_add(cnt, 1, __ATOMIC_ACQ_REL, __HIP_MEMORY_SCOPE_AGENT);
        if (a == nb - 1) {
            __hip_atomic_store(cnt, 0, __ATOMIC_RELAXED, __HIP_MEMORY_SCOPE_AGENT);
            __hip_atomic_fetch_add(gen, 1, __ATOMIC_RELEASE, __HIP_MEMORY_SCOPE_AGENT);
        } else {
            while (__hip_atomic_load(gen, __ATOMIC_ACQUIRE, __HIP_MEMORY_SCOPE_AGENT) == g)
                __builtin_amdgcn_s_sleep(2);
        }
        __threadfence();                    // acquire: invalidate stale lines
    }
    __syncthreads();
}

// ---- phase: one-pass CSR build (count + fixed-capacity slot place) --------
__device__ __forceinline__ void build_phase(const MegaArgs& a) {
    int idx = blockIdx.x * MEGA_THREADS + threadIdx.x;
    int stride = gridDim.x * MEGA_THREADS;
    for (int i = idx; i < a.E; i += stride) {
        int s = a.src[i];
        int k = a.dst[i] * NSB + s / a.npb;
        int p = atomicAdd(&a.cnt16[k], 1);
        if (p < CAP) a.es[(size_t)k * CAP + p] = s;   // clamp: memory-safe
    }
}

// ---- phase: dual GEMM (S fp32 + P bf16), 64-row tiles, grid-strided -------
// All 1024 threads stage one 64x64 fp32 tile per array in a single pass;
// team tid<256 computes the proven 4x4-register scheme. FUSE (K==64):
// X row = relu(S + Hn/deg) on the fly. Epilogue zeroes Hn for next agg.
template <int K, bool FUSE>
__device__ void gemm_phase(const MegaArgs& a, const float* __restrict__ X,
                           const float* __restrict__ Ws_g,
                           const float* __restrict__ Wn_g,
                           const float* __restrict__ bias, char* smem) {
    float (*Xs)[68] = reinterpret_cast<float (*)[68]>(smem);
    float (*Ws)[68] = reinterpret_cast<float (*)[68]>(smem + 17408);
    float (*Wn)[68] = reinterpret_cast<float (*)[68]>(smem + 34816);
    const int tid = threadIdx.x;
    const int cx = tid & 15;
    const int ry = (tid >> 4) & 15;
    const int ntiles = (a.M + 63) >> 6;

    for (int tile = blockIdx.x; tile < ntiles; tile += gridDim.x) {
        const int row0 = tile * 64;
        float acc_s[4][4] = {{0.f}};
        float acc_n[4][4] = {{0.f}};

        for (int kc = 0; kc < K; kc += 64) {
            {   // stage by all 1024 threads: row=tid>>4 (0..63), k4=(tid&15)*4
                int row = tid >> 4;
                int k4  = (tid & 15) * 4;
                int gr = row0 + row;
                float4 xv = make_float4(0.f, 0.f, 0.f, 0.f);
                if (gr < a.M) {
                    xv = *reinterpret_cast<const float4*>(&X[(size_t)gr * K + kc + k4]);
                    if constexpr (FUSE) {   // K==64, kc==0
                        float4 hv = *reinterpret_cast<const float4*>(&a.Hn[(size_t)gr * DH + k4]);
                        float inv = 1.f / fmaxf((float)degN(a.cnt16, gr), 1.f);
                        xv.x = fmaxf(fmaf(hv.x, inv, xv.x), 0.f);
                        xv.y = fmaxf(fmaf(hv.y, inv, xv.y), 0.f);
                        xv.z = fmaxf(fmaf(hv.z, inv, xv.z), 0.f);
                        xv.w = fmaxf(fmaf(hv.w, inv, xv.w), 0.f);
                    }
                }
                *reinterpret_cast<float4*>(&Xs[row][k4]) = xv;
                *reinterpret_cast<float4*>(&Ws[row][k4]) =
                    *reinterpret_cast<const float4*>(&Ws_g[(size_t)(kc + row) * 64 + k4]);
                *reinterpret_cast<float4*>(&Wn[row][k4]) =
                    *reinterpret_cast<const float4*>(&Wn_g[(size_t)(kc + row) * 64 + k4]);
            }
            __syncthreads();
            if (tid < 256) {
#pragma unroll 4
                for (int kk = 0; kk < 64; ++kk) {
                    float av[4], bs[4], bn[4];
#pragma unroll
                    for (int j = 0; j < 4; ++j) av[j] = Xs[ry * 4 + j][kk];
#pragma unroll
                    for (int i = 0; i < 4; ++i) {
                        bs[i] = Ws[kk][cx + 16 * i];
                        bn[i] = Wn[kk][cx + 16 * i];
                    }
#pragma unroll
                    for (int j = 0; j < 4; ++j)
#pragma unroll
                        for (int i = 0; i < 4; ++i) {
                            acc_s[j][i] += av[j] * bs[i];
                            acc_n[j][i] += av[j] * bn[i];
                        }
                }
            }
            __syncthreads();
        }
        if (tid < 256) {
#pragma unroll
            for (int j = 0; j < 4; ++j) {
                int r = row0 + ry * 4 + j;
                if (r < a.M) {
#pragma unroll
                    for (int i = 0; i < 4; ++i) {
                        int col = cx + 16 * i;
                        a.S[(size_t)r * DH + col] = acc_s[j][i] + bias[col];
                        a.P[(size_t)r * DH + col] = f2bf(acc_n[j][i]);
                        a.Hn[(size_t)r * DH + col] = 0.f;
                    }
                }
            }
        }
    }
}

// ---- phase: aggregation (src-bucket LDS slice, wave-per-(dst,bucket)) -----
// block = (bucket sb, dst-tile): stage 625 rows x 128B = 80,000B once,
// wave-per-dst gathers full 64-dim rows from LDS, one coalesced 256B
// atomicAdd into Hn per nonempty (dst,bucket).
__device__ void agg_phase(const MegaArgs& a, char* smem) {
    unsigned short* sP = reinterpret_cast<unsigned short*>(smem);
    const int tid = threadIdx.x;
    const int sb    = blockIdx.x & (NSB - 1);
    const int dtile = blockIdx.x >> 4;
    const int s0 = sb * a.npb;
    const int snodes = min(a.npb, a.M - s0);

    {   // stage this bucket's P slice (coalesced uint4)
        const uint4* gp = reinterpret_cast<const uint4*>(a.P + (size_t)s0 * DH);
        int cnt = snodes * 8;   // 128 B/node / 16 B
        for (int j = tid; j < cnt; j += MEGA_THREADS)
            *reinterpret_cast<uint4*>(&sP[j * 8]) = gp[j];
    }
    __syncthreads();

    const int lane = tid & 63, wv = tid >> 6;
    int dpb  = (a.M + DTILES - 1) / DTILES;
    int d0t  = dtile * dpb;
    int dend = min(d0t + dpb, a.M);

    for (int dstn = d0t + wv; dstn < dend; dstn += 16) {
        int key = dstn * NSB + sb;
        int cnt = min(a.cnt16[key], CAP);
        if (cnt == 0) continue;
        size_t base = (size_t)key * CAP;
        float acc = 0.f;
        int cmax = cnt - 1;
        for (int e = 0; e < cnt; e += 4) {
            int i0 = a.es[base + min(e + 0, cmax)] - s0;
            int i1 = a.es[base + min(e + 1, cmax)] - s0;
            int i2 = a.es[base + min(e + 2, cmax)] - s0;
            int i3 = a.es[base + min(e + 3, cmax)] - s0;
            float m1 = (e + 1 < cnt) ? 1.f : 0.f;
            float m2 = (e + 2 < cnt) ? 1.f : 0.f;
            float m3 = (e + 3 < cnt) ? 1.f : 0.f;
            float f0 = bfu(sP[(size_t)i0 * DH + lane]);
            float f1 = bfu(sP[(size_t)i1 * DH + lane]);
            float f2 = bfu(sP[(size_t)i2 * DH + lane]);
            float f3 = bfu(sP[(size_t)i3 * DH + lane]);
            acc += f0;                       // e+0 always valid in-loop
            acc = fmaf(m1, f1, acc);
            acc = fmaf(m2, f2, acc);
            acc = fmaf(m3, f3, acc);
        }
        atomicAdd(&a.Hn[(size_t)dstn * DH + lane], acc);   // coalesced 256 B
    }
    __syncthreads();   // smem reuse safety
}

// ---- phase: layer-3 finish (H = S + Hn/deg) + readout accumulation --------
// 640 active waves transposed across blocks; per-wave register accumulation
// (graph_id sorted), one coalesced flush per graph-change (R10 profile).
__device__ void finish_phase(const MegaArgs& a) {
    const int lane = threadIdx.x & 63;
    const int wv = threadIdx.x >> 6;
    int wid = blockIdx.x + MEGA_BLOCKS * wv;
    if (wid >= NW_FIN) return;
    int cpw = (a.M + NW_FIN - 1) / NW_FIN;
    int n0 = wid * cpw, n1 = min(n0 + cpw, a.M);
    if (n0 >= n1) return;

    float acc = 0.f;
    int cnt = 0;
    int cur = a.graph_id[n0];
    for (int n = n0; n < n1; ++n) {
        int gid = a.graph_id[n];
        if (gid != cur) {
            atomicAdd(&a.gsum[cur * DH + lane], acc);
            if (lane == 0) atomicAdd(&a.gcnt[cur], (float)cnt);
            acc = 0.f; cnt = 0; cur = gid;
        }
        float inv = 1.f / fmaxf((float)degN(a.cnt16, n), 1.f);
        size_t o = (size_t)n * DH + lane;
        float val = fmaf(a.Hn[o], inv, a.S[o]);
        a.H[o] = val;
        acc += val;
        ++cnt;
    }
    atomicAdd(&a.gsum[cur * DH + lane], acc);
    if (lane == 0) atomicAdd(&a.gcnt[cur], (float)cnt);
}

// ---- phase: readout (block 0) ---------------------------------------------
__device__ void readout_phase(const MegaArgs& a, char* smem) {
    if (blockIdx.x != 0) return;
    float (*ofs)[DH] = reinterpret_cast<float (*)[DH]>(smem);
    int tid = threadIdx.x;
    int g = tid >> 6, d = tid & 63;
    float of = a.gsum[tid] / fmaxf(a.gcnt[g], 1.0f);
    a.out_feat[tid] = of;
    ofs[g][d] = of;
    __syncthreads();
    if (tid < NG * 2) {
        int gg = tid >> 1, cc = tid & 1;
        float accv = a.bc[cc];
#pragma unroll 8
        for (int dd = 0; dd < DH; ++dd) accv += ofs[gg][dd] * a.Wc[dd * 2 + cc];
        a.out[gg * 2 + cc] = accv;
    }
}

// ---- the persistent mega kernel (plain launch, graph-capturable) ----------
// 256 blocks x 1024 thr, 80KB LDS, __launch_bounds__(1024,8) -> 2 blocks/CU
// capacity: all 256 blocks resident needing only 128 of 256 CUs.
__global__ __launch_bounds__(MEGA_THREADS, 8) void mega_kernel(MegaArgs a) {
    __shared__ __align__(16) char smem[80000];
    int* bcnt = a.bar;
    int* bgen = a.bar + 1;
    const int nb = gridDim.x;

    build_phase(a);                                           // writes cnt16/es
    gemm_phase<256, false>(a, a.feat, a.Ws1, a.Wn1, a.b1, smem);  // independent
    grid_sync(bcnt, bgen, nb);
    agg_phase(a, smem);
    grid_sync(bcnt, bgen, nb);
    gemm_phase<64, true>(a, a.S, a.Ws2, a.Wn2, a.b2, smem);
    grid_sync(bcnt, bgen, nb);
    agg_phase(a, smem);
    grid_sync(bcnt, bgen, nb);
    gemm_phase<64, true>(a, a.S, a.Ws3, a.Wn3, a.b3, smem);
    grid_sync(bcnt, bgen, nb);
    agg_phase(a, smem);
    grid_sync(bcnt, bgen, nb);
    finish_phase(a);
    grid_sync(bcnt, bgen, nb);
    readout_phase(a, smem);
}

extern "C" void kernel_launch(void* const* d_in, const int* in_sizes, int n_in,
                              void* d_out, int out_size, void* d_ws, size_t ws_size,
                              hipStream_t stream) {
    const float* feat     = (const float*)d_in[0];
    const int*   src      = (const int*)d_in[1];
    const int*   dst      = (const int*)d_in[2];
    const int*   graph_id = (const int*)d_in[3];
    const float* Ws1 = (const float*)d_in[4];
    const float* Wn1 = (const float*)d_in[5];
    const float* b1  = (const float*)d_in[6];
    const float* Ws2 = (const float*)d_in[7];
    const float* Wn2 = (const float*)d_in[8];
    const float* b2  = (const float*)d_in[9];
    const float* Ws3 = (const float*)d_in[10];
    const float* Wn3 = (const float*)d_in[11];
    const float* b3  = (const float*)d_in[12];
    const float* Wc  = (const float*)d_in[13];
    const float* bc  = (const float*)d_in[14];

    const int M  = in_sizes[3];         // 10000 nodes
    const int E  = in_sizes[1];         // 320000 edges
    const int M2 = M * NSB;             // 160000 (dst,bucket) rows
    const int npb = (M + NSB - 1) / NSB;   // 625 (<= MAXNPB)

    float* out      = (float*)d_out;             // 16 x 2
    float* out_feat = out + NG * 2;              // 16 x 64
    float* Hbuf     = out_feat + NG * DH;        // 10000 x 64 (final h)

    // workspace layout (256B-aligned carves)
    char* w = (char*)d_ws;
    size_t off = 0;
    auto carve = [&](size_t bytes) {
        size_t o = off;
        off = (off + bytes + 255) & ~(size_t)255;
        return o;
    };
    int*   cnt16 = (int*)  (w + carve((size_t)M2 * 4));         // 640 KB
    float* gsum  = (float*)(w + carve((size_t)NG * DH * 4));
    float* gcnt  = (float*)(w + carve((size_t)NG * 4));
    int*   bar   = (int*)  (w + carve(2 * 4));
    size_t zero_bytes = off;                     // cnt16 + gsum + gcnt + bar
    int*   es    = (int*)  (w + carve((size_t)M2 * CAP * 4));   // 20.5 MB
    float* Sbuf  = (float*)(w + carve((size_t)M * DH * 4));
    unsigned short* Pbuf = (unsigned short*)(w + carve((size_t)M * DH * 2));
    float* Hn    = (float*)(w + carve((size_t)M * DH * 4));
    (void)ws_size; (void)n_in; (void)out_size;

    // barrier counters + cnt16 + readout accumulators must start at 0
    (void)hipMemsetAsync(d_ws, 0, zero_bytes, stream);

    MegaArgs a;
    a.feat = feat; a.src = src; a.dst = dst; a.graph_id = graph_id;
    a.Ws1 = Ws1; a.Wn1 = Wn1; a.b1 = b1;
    a.Ws2 = Ws2; a.Wn2 = Wn2; a.b2 = b2;
    a.Ws3 = Ws3; a.Wn3 = Wn3; a.b3 = b3;
    a.Wc = Wc; a.bc = bc;
    a.cnt16 = cnt16; a.es = es; a.bar = bar;
    a.S = Sbuf; a.P = Pbuf; a.Hn = Hn;
    a.out = out; a.out_feat = out_feat; a.H = Hbuf;
    a.gsum = gsum; a.gcnt = gcnt;
    a.M = M; a.E = E; a.npb = npb;

    mega_kernel<<<MEGA_BLOCKS, MEGA_THREADS, 0, stream>>>(a);
}

// Round 7
// 524.042 us; speedup vs baseline: 1.6721x; 1.6721x over previous
//
#include <hip/hip_runtime.h>

// ---------------------------------------------------------------------------
// SAGE 3-layer GNN — single persistent kernel with software grid barriers.
//   Per layer: S = X@W_self + b (fp32) ; P = X@W_neigh (bf16 row-major)
//              h[i] = act( S[i] + (sum_{j in N_in(i)} P[j]) / max(deg_i,1) )
//
// Evidence log:
//   R0..R5: global random row-gather agg ~150us. Wall = per-CU random-gather
//     service rate (~274 cyc/edge/CU), not bytes (R7 bf16 neutral).
//   R8 FAILED: dim-sliced LDS planes multiplied edge visits x32.
//   R9 WIN: src-bucket LDS slicing (bucket P-slice in LDS, CSR keyed
//     dst*NSB+bucket, wave-per-row LDS gather, coalesced 256B Hn atomics).
//   R10 WIN: finish 130us->off-list (sorted graph_id, per-wave register acc,
//     one coalesced flush per graph-change).
//   R11 WIN: CSR build 3 kernels -> 1 (fixed-capacity slot rows). 255.9us.
//     Accounting: ~100us of remaining 213 = dispatch serialization.
//   R12 FAILED (container died): hipLaunchCooperativeKernel + graph capture.
//   R13 FAILED (mega 821us, FETCH 63MB, WRITE 210MB, VALU 6%): barrier spin
//     polled with AGENT-scope ACQUIRE loads -> each poll invalidates the
//     XCD's L2 (non-coherent L2s) -> continuous invalidation storm destroys
//     co-located blocks' locality; everything refetches from HBM at ~900cyc.
//   R14 (this round): barrier protocol fixed to invalidate ONCE per block
//     per barrier: RELEASE fence (wbl2) -> RELAXED arrive/flip (atomics at
//     coherence point, no cache effects) -> RELAXED poll + s_sleep(16) ->
//     single ACQUIRE fence (inv) after exit. Split fences via
//     __builtin_amdgcn_fence(order,"agent"). Nothing else changed.
//   Predicted: mega 821 -> ~130-180us, FETCH 63 -> 25-40MB, total -> 160-210.
//   Contingency: mega >250us -> persistent-kernel loses; revert R11.
// ---------------------------------------------------------------------------

#define DH 64
#define NG 16
#define NSB 16       // src buckets
#define DTILES 16    // dst tiles -> 16*16 = 256 blocks
#define MAXNPB 625   // nodes per bucket (M <= 10000)
#define CAP 32       // edge slots per (dst,bucket) row; Poisson(2) tail ~4e-17
#define MEGA_BLOCKS 256
#define MEGA_THREADS 1024
#define NW_FIN 640   // finish-phase active waves (R10-proven contention)

#if __has_builtin(__builtin_amdgcn_fence)
#define REL_FENCE() __builtin_amdgcn_fence(__ATOMIC_RELEASE, "agent")
#define ACQ_FENCE() __builtin_amdgcn_fence(__ATOMIC_ACQUIRE, "agent")
#else
#define REL_FENCE() __threadfence()
#define ACQ_FENCE() __threadfence()
#endif

__device__ __forceinline__ unsigned short f2bf(float f) {
    unsigned int u = __float_as_uint(f);
    unsigned int r = (u + 0x7FFFu + ((u >> 16) & 1u)) >> 16;   // RNE
    return (unsigned short)r;
}
__device__ __forceinline__ float bfu(unsigned short v) {
    return __uint_as_float(((unsigned int)v) << 16);
}
__device__ __forceinline__ int degN(const int* __restrict__ cnt, int n) {
    const int4* cp = reinterpret_cast<const int4*>(&cnt[n * NSB]);
    int4 c0 = cp[0], c1 = cp[1], c2 = cp[2], c3 = cp[3];
    return c0.x + c0.y + c0.z + c0.w + c1.x + c1.y + c1.z + c1.w +
           c2.x + c2.y + c2.z + c2.w + c3.x + c3.y + c3.z + c3.w;
}

struct MegaArgs {
    const float* feat; const int* src; const int* dst; const int* graph_id;
    const float* Ws1; const float* Wn1; const float* b1;
    const float* Ws2; const float* Wn2; const float* b2;
    const float* Ws3; const float* Wn3; const float* b3;
    const float* Wc; const float* bc;
    int* cnt16; int* es; int* bar;      // bar[0]=arrive count, bar[1]=generation
    float* S; unsigned short* P; float* Hn;
    float* out; float* out_feat; float* H;
    float* gsum; float* gcnt;
    int M, E, npb;
};

// ---- software grid barrier (sense-reversal; cache-friendly protocol) ------
// All 256 blocks resident (1 block/CU, LDS-forced). Protocol per block:
//   REL fence (L2 writeback, once) -> RELAXED arrive (coherence-point atomic,
//   no cache effect) -> RELAXED poll + s_sleep (no cache effect) ->
//   ACQ fence (L2 invalidate, ONCE after exit).
// R13's bug: ACQUIRE per poll = continuous whole-L2 invalidation storm.
__device__ __forceinline__ void grid_sync(int* cnt, int* gen, int nb) {
    __syncthreads();
    if (threadIdx.x == 0) {
        REL_FENCE();                        // publish this XCD's dirty lines
        int g = __hip_atomic_load(gen, __ATOMIC_RELAXED, __HIP_MEMORY_SCOPE_AGENT);
        int a = __hip_atomic_fetch_add(cnt, 1, __ATOMIC_RELAXED, __HIP_MEMORY_SCOPE_AGENT);
        if (a == nb - 1) {
            __hip_atomic_store(cnt, 0, __ATOMIC_RELAXED, __HIP_MEMORY_SCOPE_AGENT);
            __hip_atomic_store(gen, g + 1, __ATOMIC_RELAXED, __HIP_MEMORY_SCOPE_AGENT);
        } else {
            while (__hip_atomic_load(gen, __ATOMIC_RELAXED, __HIP_MEMORY_SCOPE_AGENT) == g)
                __builtin_amdgcn_s_sleep(16);   // ~1K cyc poll, no cache traffic
        }
        ACQ_FENCE();                        // drop stale lines exactly once
    }
    __syncthreads();
}

// ---- phase: one-pass CSR build (count + fixed-capacity slot place) --------
__device__ __forceinline__ void build_phase(const MegaArgs& a) {
    int idx = blockIdx.x * MEGA_THREADS + threadIdx.x;
    int stride = gridDim.x * MEGA_THREADS;
    for (int i = idx; i < a.E; i += stride) {
        int s = a.src[i];
        int k = a.dst[i] * NSB + s / a.npb;
        int p = atomicAdd(&a.cnt16[k], 1);
        if (p < CAP) a.es[(size_t)k * CAP + p] = s;   // clamp: memory-safe
    }
}

// ---- phase: dual GEMM (S fp32 + P bf16), 64-row tiles, grid-strided -------
// All 1024 threads stage one 64x64 fp32 tile per array in a single pass;
// team tid<256 computes the proven 4x4-register scheme. FUSE (K==64):
// X row = relu(S + Hn/deg) on the fly. Epilogue zeroes Hn for next agg.
template <int K, bool FUSE>
__device__ void gemm_phase(const MegaArgs& a, const float* __restrict__ X,
                           const float* __restrict__ Ws_g,
                           const float* __restrict__ Wn_g,
                           const float* __restrict__ bias, char* smem) {
    float (*Xs)[68] = reinterpret_cast<float (*)[68]>(smem);
    float (*Ws)[68] = reinterpret_cast<float (*)[68]>(smem + 17408);
    float (*Wn)[68] = reinterpret_cast<float (*)[68]>(smem + 34816);
    const int tid = threadIdx.x;
    const int cx = tid & 15;
    const int ry = (tid >> 4) & 15;
    const int ntiles = (a.M + 63) >> 6;

    for (int tile = blockIdx.x; tile < ntiles; tile += gridDim.x) {
        const int row0 = tile * 64;
        float acc_s[4][4] = {{0.f}};
        float acc_n[4][4] = {{0.f}};

        for (int kc = 0; kc < K; kc += 64) {
            {   // stage by all 1024 threads: row=tid>>4 (0..63), k4=(tid&15)*4
                int row = tid >> 4;
                int k4  = (tid & 15) * 4;
                int gr = row0 + row;
                float4 xv = make_float4(0.f, 0.f, 0.f, 0.f);
                if (gr < a.M) {
                    xv = *reinterpret_cast<const float4*>(&X[(size_t)gr * K + kc + k4]);
                    if constexpr (FUSE) {   // K==64, kc==0
                        float4 hv = *reinterpret_cast<const float4*>(&a.Hn[(size_t)gr * DH + k4]);
                        float inv = 1.f / fmaxf((float)degN(a.cnt16, gr), 1.f);
                        xv.x = fmaxf(fmaf(hv.x, inv, xv.x), 0.f);
                        xv.y = fmaxf(fmaf(hv.y, inv, xv.y), 0.f);
                        xv.z = fmaxf(fmaf(hv.z, inv, xv.z), 0.f);
                        xv.w = fmaxf(fmaf(hv.w, inv, xv.w), 0.f);
                    }
                }
                *reinterpret_cast<float4*>(&Xs[row][k4]) = xv;
                *reinterpret_cast<float4*>(&Ws[row][k4]) =
                    *reinterpret_cast<const float4*>(&Ws_g[(size_t)(kc + row) * 64 + k4]);
                *reinterpret_cast<float4*>(&Wn[row][k4]) =
                    *reinterpret_cast<const float4*>(&Wn_g[(size_t)(kc + row) * 64 + k4]);
            }
            __syncthreads();
            if (tid < 256) {
#pragma unroll 4
                for (int kk = 0; kk < 64; ++kk) {
                    float av[4], bs[4], bn[4];
#pragma unroll
                    for (int j = 0; j < 4; ++j) av[j] = Xs[ry * 4 + j][kk];
#pragma unroll
                    for (int i = 0; i < 4; ++i) {
                        bs[i] = Ws[kk][cx + 16 * i];
                        bn[i] = Wn[kk][cx + 16 * i];
                    }
#pragma unroll
                    for (int j = 0; j < 4; ++j)
#pragma unroll
                        for (int i = 0; i < 4; ++i) {
                            acc_s[j][i] += av[j] * bs[i];
                            acc_n[j][i] += av[j] * bn[i];
                        }
                }
            }
            __syncthreads();
        }
        if (tid < 256) {
#pragma unroll
            for (int j = 0; j < 4; ++j) {
                int r = row0 + ry * 4 + j;
                if (r < a.M) {
#pragma unroll
                    for (int i = 0; i < 4; ++i) {
                        int col = cx + 16 * i;
                        a.S[(size_t)r * DH + col] = acc_s[j][i] + bias[col];
                        a.P[(size_t)r * DH + col] = f2bf(acc_n[j][i]);
                        a.Hn[(size_t)r * DH + col] = 0.f;
                    }
                }
            }
        }
    }
}

// ---- phase: aggregation (src-bucket LDS slice, wave-per-(dst,bucket)) -----
// block = (bucket sb, dst-tile): stage 625 rows x 128B = 80,000B once,
// wave-per-dst gathers full 64-dim rows from LDS, one coalesced 256B
// atomicAdd into Hn per nonempty (dst,bucket).
__device__ void agg_phase(const MegaArgs& a, char* smem) {
    unsigned short* sP = reinterpret_cast<unsigned short*>(smem);
    const int tid = threadIdx.x;
    const int sb    = blockIdx.x & (NSB - 1);
    const int dtile = blockIdx.x >> 4;
    const int s0 = sb * a.npb;
    const int snodes = min(a.npb, a.M - s0);

    {   // stage this bucket's P slice (coalesced uint4)
        const uint4* gp = reinterpret_cast<const uint4*>(a.P + (size_t)s0 * DH);
        int cnt = snodes * 8;   // 128 B/node / 16 B
        for (int j = tid; j < cnt; j += MEGA_THREADS)
            *reinterpret_cast<uint4*>(&sP[j * 8]) = gp[j];
    }
    __syncthreads();

    const int lane = tid & 63, wv = tid >> 6;
    int dpb  = (a.M + DTILES - 1) / DTILES;
    int d0t  = dtile * dpb;
    int dend = min(d0t + dpb, a.M);

    for (int dstn = d0t + wv; dstn < dend; dstn += 16) {
        int key = dstn * NSB + sb;
        int cnt = min(a.cnt16[key], CAP);
        if (cnt == 0) continue;
        size_t base = (size_t)key * CAP;
        float acc = 0.f;
        int cmax = cnt - 1;
        for (int e = 0; e < cnt; e += 4) {
            int i0 = a.es[base + min(e + 0, cmax)] - s0;
            int i1 = a.es[base + min(e + 1, cmax)] - s0;
            int i2 = a.es[base + min(e + 2, cmax)] - s0;
            int i3 = a.es[base + min(e + 3, cmax)] - s0;
            float m1 = (e + 1 < cnt) ? 1.f : 0.f;
            float m2 = (e + 2 < cnt) ? 1.f : 0.f;
            float m3 = (e + 3 < cnt) ? 1.f : 0.f;
            float f0 = bfu(sP[(size_t)i0 * DH + lane]);
            float f1 = bfu(sP[(size_t)i1 * DH + lane]);
            float f2 = bfu(sP[(size_t)i2 * DH + lane]);
            float f3 = bfu(sP[(size_t)i3 * DH + lane]);
            acc += f0;                       // e+0 always valid in-loop
            acc = fmaf(m1, f1, acc);
            acc = fmaf(m2, f2, acc);
            acc = fmaf(m3, f3, acc);
        }
        atomicAdd(&a.Hn[(size_t)dstn * DH + lane], acc);   // coalesced 256 B
    }
    __syncthreads();   // smem reuse safety
}

// ---- phase: layer-3 finish (H = S + Hn/deg) + readout accumulation --------
// 640 active waves transposed across blocks; per-wave register accumulation
// (graph_id sorted), one coalesced flush per graph-change (R10 profile).
__device__ void finish_phase(const MegaArgs& a) {
    const int lane = threadIdx.x & 63;
    const int wv = threadIdx.x >> 6;
    int wid = blockIdx.x + MEGA_BLOCKS * wv;
    if (wid >= NW_FIN) return;
    int cpw = (a.M + NW_FIN - 1) / NW_FIN;
    int n0 = wid * cpw, n1 = min(n0 + cpw, a.M);
    if (n0 >= n1) return;

    float acc = 0.f;
    int cnt = 0;
    int cur = a.graph_id[n0];
    for (int n = n0; n < n1; ++n) {
        int gid = a.graph_id[n];
        if (gid != cur) {
            atomicAdd(&a.gsum[cur * DH + lane], acc);
            if (lane == 0) atomicAdd(&a.gcnt[cur], (float)cnt);
            acc = 0.f; cnt = 0; cur = gid;
        }
        float inv = 1.f / fmaxf((float)degN(a.cnt16, n), 1.f);
        size_t o = (size_t)n * DH + lane;
        float val = fmaf(a.Hn[o], inv, a.S[o]);
        a.H[o] = val;
        acc += val;
        ++cnt;
    }
    atomicAdd(&a.gsum[cur * DH + lane], acc);
    if (lane == 0) atomicAdd(&a.gcnt[cur], (float)cnt);
}

// ---- phase: readout (block 0) ---------------------------------------------
__device__ void readout_phase(const MegaArgs& a, char* smem) {
    if (blockIdx.x != 0) return;
    float (*ofs)[DH] = reinterpret_cast<float (*)[DH]>(smem);
    int tid = threadIdx.x;
    int g = tid >> 6, d = tid & 63;
    float of = a.gsum[tid] / fmaxf(a.gcnt[g], 1.0f);
    a.out_feat[tid] = of;
    ofs[g][d] = of;
    __syncthreads();
    if (tid < NG * 2) {
        int gg = tid >> 1, cc = tid & 1;
        float accv = a.bc[cc];
#pragma unroll 8
        for (int dd = 0; dd < DH; ++dd) accv += ofs[gg][dd] * a.Wc[dd * 2 + cc];
        a.out[gg * 2 + cc] = accv;
    }
}

// ---- the persistent mega kernel (plain launch, graph-capturable) ----------
// 256 blocks x 1024 thr, 80KB LDS -> 1 block/CU resident (grid == CU count).
__global__ __launch_bounds__(MEGA_THREADS, 8) void mega_kernel(MegaArgs a) {
    __shared__ __align__(16) char smem[80000];
    int* bcnt = a.bar;
    int* bgen = a.bar + 1;
    const int nb = gridDim.x;

    build_phase(a);                                           // writes cnt16/es
    gemm_phase<256, false>(a, a.feat, a.Ws1, a.Wn1, a.b1, smem);  // independent
    grid_sync(bcnt, bgen, nb);
    agg_phase(a, smem);
    grid_sync(bcnt, bgen, nb);
    gemm_phase<64, true>(a, a.S, a.Ws2, a.Wn2, a.b2, smem);
    grid_sync(bcnt, bgen, nb);
    agg_phase(a, smem);
    grid_sync(bcnt, bgen, nb);
    gemm_phase<64, true>(a, a.S, a.Ws3, a.Wn3, a.b3, smem);
    grid_sync(bcnt, bgen, nb);
    agg_phase(a, smem);
    grid_sync(bcnt, bgen, nb);
    finish_phase(a);
    grid_sync(bcnt, bgen, nb);
    readout_phase(a, smem);
}

extern "C" void kernel_launch(void* const* d_in, const int* in_sizes, int n_in,
                              void* d_out, int out_size, void* d_ws, size_t ws_size,
                              hipStream_t stream) {
    const float* feat     = (const float*)d_in[0];
    const int*   src      = (const int*)d_in[1];
    const int*   dst      = (const int*)d_in[2];
    const int*   graph_id = (const int*)d_in[3];
    const float* Ws1 = (const float*)d_in[4];
    const float* Wn1 = (const float*)d_in[5];
    const float* b1  = (const float*)d_in[6];
    const float* Ws2 = (const float*)d_in[7];
    const float* Wn2 = (const float*)d_in[8];
    const float* b2  = (const float*)d_in[9];
    const float* Ws3 = (const float*)d_in[10];
    const float* Wn3 = (const float*)d_in[11];
    const float* b3  = (const float*)d_in[12];
    const float* Wc  = (const float*)d_in[13];
    const float* bc  = (const float*)d_in[14];

    const int M  = in_sizes[3];         // 10000 nodes
    const int E  = in_sizes[1];         // 320000 edges
    const int M2 = M * NSB;             // 160000 (dst,bucket) rows
    const int npb = (M + NSB - 1) / NSB;   // 625 (<= MAXNPB)

    float* out      = (float*)d_out;             // 16 x 2
    float* out_feat = out + NG * 2;              // 16 x 64
    float* Hbuf     = out_feat + NG * DH;        // 10000 x 64 (final h)

    // workspace layout (256B-aligned carves)
    char* w = (char*)d_ws;
    size_t off = 0;
    auto carve = [&](size_t bytes) {
        size_t o = off;
        off = (off + bytes + 255) & ~(size_t)255;
        return o;
    };
    int*   cnt16 = (int*)  (w + carve((size_t)M2 * 4));         // 640 KB
    float* gsum  = (float*)(w + carve((size_t)NG * DH * 4));
    float* gcnt  = (float*)(w + carve((size_t)NG * 4));
    int*   bar   = (int*)  (w + carve(2 * 4));
    size_t zero_bytes = off;                     // cnt16 + gsum + gcnt + bar
    int*   es    = (int*)  (w + carve((size_t)M2 * CAP * 4));   // 20.5 MB
    float* Sbuf  = (float*)(w + carve((size_t)M * DH * 4));
    unsigned short* Pbuf = (unsigned short*)(w + carve((size_t)M * DH * 2));
    float* Hn    = (float*)(w + carve((size_t)M * DH * 4));
    (void)ws_size; (void)n_in; (void)out_size;

    // barrier counters + cnt16 + readout accumulators must start at 0
    (void)hipMemsetAsync(d_ws, 0, zero_bytes, stream);

    MegaArgs a;
    a.feat = feat; a.src = src; a.dst = dst; a.graph_id = graph_id;
    a.Ws1 = Ws1; a.Wn1 = Wn1; a.b1 = b1;
    a.Ws2 = Ws2; a.Wn2 = Wn2; a.b2 = b2;
    a.Ws3 = Ws3; a.Wn3 = Wn3; a.b3 = b3;
    a.Wc = Wc; a.bc = bc;
    a.cnt16 = cnt16; a.es = es; a.bar = bar;
    a.S = Sbuf; a.P = Pbuf; a.Hn = Hn;
    a.out = out; a.out_feat = out_feat; a.H = Hbuf;
    a.gsum = gsum; a.gcnt = gcnt;
    a.M = M; a.E = E; a.npb = npb;

    mega_kernel<<<MEGA_BLOCKS, MEGA_THREADS, 0, stream>>>(a);
}

// Round 8
// 249.126 us; speedup vs baseline: 3.5172x; 2.1035x over previous
//
#include <hip/hip_runtime.h>

// ---------------------------------------------------------------------------
// SAGE 3-layer GNN.  (R15 = R11-proven pipeline + 2 dispatch fusions)
//   Per layer: S = X@W_self + b (fp32) ; P = X@W_neigh (bf16 row-major)
//              h[i] = act( S[i] + (sum_{j in N_in(i)} P[j]) / max(deg_i,1) )
//
// Evidence log:
//   R0..R5: global random row-gather agg ~150us. Wall = per-CU random-gather
//     service rate (~274 cyc/edge/CU), not bytes (R7 bf16 neutral).
//   R8 FAILED: dim-sliced LDS planes multiplied edge visits x32.
//   R9 WIN: src-bucket LDS slicing (8 buckets x 1250 rows x 128B in LDS,
//     CSR keyed dst*8+bucket, wave-per-row, coalesced 256B Hn atomics).
//   R10 WIN: finish 130us->off-list (sorted graph_id, per-wave register acc,
//     one coalesced flush per graph-change).
//   R11 WIN: CSR build 3 kernels -> 1 (fixed-cap 32-slot rows). 255.9us.
//   R12 FAILED: hipLaunchCooperativeKernel killed the container (capture).
//   R13 FAILED (821us): barrier spin with per-poll AGENT ACQUIRE loads =
//     continuous L2 invalidation storm.
//   R14 PARTIAL (441us): once-per-barrier fences fixed the spin cost, but
//     FETCH/WRITE unchanged (63/207MB @ 612GB/s sustained) -> persistent
//     kernel's floor is structurally above multi-kernel: NSB=16 doubled
//     Hn atomic RMW rows (coherence-point serialized; L2s non-coherent),
//     es line-granularity waste, and per-barrier L2 invalidation refetch.
//     Pre-committed contingency: mega>250us -> REVERT to R11.
//   R15 (this round): R11 exactly, plus (1) build fused into gemm1 dispatch
//     (independent work, heterogeneous blocks); (2) readout fused into
//     finish via last-block-done ticket (once-per-block fence+atomic).
//     10 dispatches -> 8. Next lever queued: atomic-free agg via per-bucket
//     Hn partial planes.
//   Predicted: 255.9 -> ~230-245us; top-5 stays harness-fill-only.
// ---------------------------------------------------------------------------

#define DH 64
#define NG 16
#define NSB 8        // src buckets
#define DTILES 32    // dst tiles -> grid 8*32 = 256 agg blocks (1/CU)
#define MAXNPB 1250  // max nodes per bucket (M <= 10000)
#define CAP 32       // edge slots per (dst,bucket) row; Poisson(4) tail ~1e-19

__device__ __forceinline__ unsigned short f2bf(float f) {
    unsigned int u = __float_as_uint(f);
    unsigned int r = (u + 0x7FFFu + ((u >> 16) & 1u)) >> 16;   // RNE
    return (unsigned short)r;
}
__device__ __forceinline__ float bfu(unsigned short v) {
    return __uint_as_float(((unsigned int)v) << 16);
}
__device__ __forceinline__ int deg8(const int* __restrict__ cnt8, int n) {
    const int4* cp = reinterpret_cast<const int4*>(&cnt8[n * NSB]);
    int4 c0 = cp[0], c1 = cp[1];
    return c0.x + c0.y + c0.z + c0.w + c1.x + c1.y + c1.z + c1.w;
}

// ---- fused: dual GEMM layer-1 (blocks [0,gb)) + CSR build ([gb,gb+eb)) ----
// gemm: S = X@Ws + b (fp32), P = X@Wn (bf16), epilogue zeroes Hn.
// build: one edge sweep, p=atomicAdd(cnt8[key]); es[key*CAP+p]=src (clamped).
// Independent outputs; consumers start next dispatch.
__global__ __launch_bounds__(256) void gemm1_build_kernel(
    const float* __restrict__ X, const float* __restrict__ Ws_g,
    const float* __restrict__ Wn_g, const float* __restrict__ bias,
    float* __restrict__ S, unsigned short* __restrict__ P,
    float* __restrict__ Hn_out,
    const int* __restrict__ src, const int* __restrict__ dst,
    int* __restrict__ cnt8, int* __restrict__ es,
    int M, int E, int npb8, int gb) {
    constexpr int K = 256;
    int tid = threadIdx.x;

    if ((int)blockIdx.x >= gb) {          // ---- build part ----
        int i = ((int)blockIdx.x - gb) * 256 + tid;
        if (i < E) {
            int s = src[i];
            int k = dst[i] * NSB + s / npb8;
            int p = atomicAdd(&cnt8[k], 1);
            if (p < CAP) es[(size_t)k * CAP + p] = s;   // clamp: memory-safe
        }
        return;
    }

    // ---- gemm part (R11-proven body, K=256, no FUSE) ----
    __shared__ float Xs[64][68];
    __shared__ float Ws[64][68];
    __shared__ float Wn[64][68];
    int row0 = blockIdx.x * 64;
    int cx = tid & 15;
    int ry = tid >> 4;
    float acc_s[4][4] = {{0.f}};
    float acc_n[4][4] = {{0.f}};

    for (int kc = 0; kc < K; kc += 64) {
#pragma unroll
        for (int it = 0; it < 4; ++it) {
            int q = tid + 256 * it;
            int row = q >> 4;
            int k4 = (q & 15) * 4;
            float4 xv = make_float4(0.f, 0.f, 0.f, 0.f);
            int gr = row0 + row;
            if (gr < M)
                xv = *reinterpret_cast<const float4*>(&X[(size_t)gr * K + kc + k4]);
            *reinterpret_cast<float4*>(&Xs[row][k4]) = xv;
            float4 wv = *reinterpret_cast<const float4*>(&Ws_g[(size_t)(kc + row) * 64 + k4]);
            *reinterpret_cast<float4*>(&Ws[row][k4]) = wv;
            float4 nv = *reinterpret_cast<const float4*>(&Wn_g[(size_t)(kc + row) * 64 + k4]);
            *reinterpret_cast<float4*>(&Wn[row][k4]) = nv;
        }
        __syncthreads();
#pragma unroll 4
        for (int kk = 0; kk < 64; ++kk) {
            float av[4], bs[4], bn[4];
#pragma unroll
            for (int j = 0; j < 4; ++j) av[j] = Xs[ry * 4 + j][kk];
#pragma unroll
            for (int i = 0; i < 4; ++i) {
                bs[i] = Ws[kk][cx + 16 * i];
                bn[i] = Wn[kk][cx + 16 * i];
            }
#pragma unroll
            for (int j = 0; j < 4; ++j)
#pragma unroll
                for (int i = 0; i < 4; ++i) {
                    acc_s[j][i] += av[j] * bs[i];
                    acc_n[j][i] += av[j] * bn[i];
                }
        }
        __syncthreads();
    }

#pragma unroll
    for (int j = 0; j < 4; ++j) {
        int r = row0 + ry * 4 + j;
        if (r < M) {
#pragma unroll
            for (int i = 0; i < 4; ++i) {
                int col = cx + 16 * i;
                S[(size_t)r * DH + col] = acc_s[j][i] + bias[col];
                P[(size_t)r * DH + col] = f2bf(acc_n[j][i]);
                Hn_out[(size_t)r * DH + col] = 0.f;
            }
        }
    }
}

// ---- dual GEMM layers 2/3: X = relu(S + Hn/deg) fused on load -------------
__global__ __launch_bounds__(256) void gemm_dual_kernel(
    const float* __restrict__ X, const float* __restrict__ Ws_g,
    const float* __restrict__ Wn_g, const float* __restrict__ bias,
    const float* __restrict__ Hn_in, const int* __restrict__ cnt8,
    float* __restrict__ S, unsigned short* __restrict__ P,
    float* __restrict__ Hn_out, int M) {
    constexpr int K = 64;
    __shared__ float Xs[64][68];
    __shared__ float Ws[64][68];
    __shared__ float Wn[64][68];
    int tid = threadIdx.x;
    int row0 = blockIdx.x * 64;
    int cx = tid & 15;
    int ry = tid >> 4;
    float acc_s[4][4] = {{0.f}};
    float acc_n[4][4] = {{0.f}};

    {
#pragma unroll
        for (int it = 0; it < 4; ++it) {
            int q = tid + 256 * it;
            int row = q >> 4;
            int k4 = (q & 15) * 4;
            float4 xv = make_float4(0.f, 0.f, 0.f, 0.f);
            int gr = row0 + row;
            if (gr < M) {
                xv = *reinterpret_cast<const float4*>(&X[(size_t)gr * K + k4]);
                float4 hv = *reinterpret_cast<const float4*>(&Hn_in[(size_t)gr * DH + k4]);
                float inv = 1.f / fmaxf((float)deg8(cnt8, gr), 1.f);
                xv.x = fmaxf(fmaf(hv.x, inv, xv.x), 0.f);
                xv.y = fmaxf(fmaf(hv.y, inv, xv.y), 0.f);
                xv.z = fmaxf(fmaf(hv.z, inv, xv.z), 0.f);
                xv.w = fmaxf(fmaf(hv.w, inv, xv.w), 0.f);
            }
            *reinterpret_cast<float4*>(&Xs[row][k4]) = xv;
            float4 wv = *reinterpret_cast<const float4*>(&Ws_g[(size_t)row * 64 + k4]);
            *reinterpret_cast<float4*>(&Ws[row][k4]) = wv;
            float4 nv = *reinterpret_cast<const float4*>(&Wn_g[(size_t)row * 64 + k4]);
            *reinterpret_cast<float4*>(&Wn[row][k4]) = nv;
        }
        __syncthreads();
#pragma unroll 4
        for (int kk = 0; kk < 64; ++kk) {
            float av[4], bs[4], bn[4];
#pragma unroll
            for (int j = 0; j < 4; ++j) av[j] = Xs[ry * 4 + j][kk];
#pragma unroll
            for (int i = 0; i < 4; ++i) {
                bs[i] = Ws[kk][cx + 16 * i];
                bn[i] = Wn[kk][cx + 16 * i];
            }
#pragma unroll
            for (int j = 0; j < 4; ++j)
#pragma unroll
                for (int i = 0; i < 4; ++i) {
                    acc_s[j][i] += av[j] * bs[i];
                    acc_n[j][i] += av[j] * bn[i];
                }
        }
        __syncthreads();
    }

#pragma unroll
    for (int j = 0; j < 4; ++j) {
        int r = row0 + ry * 4 + j;
        if (r < M) {
#pragma unroll
            for (int i = 0; i < 4; ++i) {
                int col = cx + 16 * i;
                S[(size_t)r * DH + col] = acc_s[j][i] + bias[col];
                P[(size_t)r * DH + col] = f2bf(acc_n[j][i]);
                Hn_out[(size_t)r * DH + col] = 0.f;
            }
        }
    }
}

// ---- aggregation: src-bucket LDS slice, wave-per-(dst,bucket) row ----------
// grid = NSB * DTILES blocks x 1024 threads. LDS = 1250*64 bf16 = 160,000 B.
__global__ __launch_bounds__(1024) void agg_kernel(
    const unsigned short* __restrict__ P, const int* __restrict__ cnt8,
    const int* __restrict__ es, float* __restrict__ Hn, int M, int npb8) {
    __shared__ __align__(16) unsigned short sP[MAXNPB * DH];
    int tid = threadIdx.x;
    int sb    = blockIdx.x & (NSB - 1);
    int dtile = blockIdx.x >> 3;
    int s0 = sb * npb8;
    int snodes = min(npb8, M - s0);

    // stage this bucket's P slice (coalesced uint4)
    {
        const uint4* gp = reinterpret_cast<const uint4*>(P + (size_t)s0 * DH);
        int cnt = snodes * 8;   // 128 B/node / 16 B
        for (int j = tid; j < cnt; j += 1024)
            *reinterpret_cast<uint4*>(&sP[j * 8]) = gp[j];
    }
    __syncthreads();

    int lane = tid & 63, wid = tid >> 6;
    int dpb  = (M + DTILES - 1) / DTILES;
    int d0t  = dtile * dpb;
    int dend = min(d0t + dpb, M);

    for (int dstn = d0t + wid; dstn < dend; dstn += 16) {
        int key = dstn * NSB + sb;
        int cnt = min(cnt8[key], CAP);
        if (cnt == 0) continue;
        size_t base = (size_t)key * CAP;
        float acc = 0.f;
        int cmax = cnt - 1;
        for (int e = 0; e < cnt; e += 4) {
            int i0 = es[base + min(e + 0, cmax)] - s0;
            int i1 = es[base + min(e + 1, cmax)] - s0;
            int i2 = es[base + min(e + 2, cmax)] - s0;
            int i3 = es[base + min(e + 3, cmax)] - s0;
            float m1 = (e + 1 < cnt) ? 1.f : 0.f;
            float m2 = (e + 2 < cnt) ? 1.f : 0.f;
            float m3 = (e + 3 < cnt) ? 1.f : 0.f;
            float f0 = bfu(sP[(size_t)i0 * DH + lane]);
            float f1 = bfu(sP[(size_t)i1 * DH + lane]);
            float f2 = bfu(sP[(size_t)i2 * DH + lane]);
            float f3 = bfu(sP[(size_t)i3 * DH + lane]);
            acc += f0;                       // e+0 always valid in-loop
            acc = fmaf(m1, f1, acc);
            acc = fmaf(m2, f2, acc);
            acc = fmaf(m3, f3, acc);
        }
        atomicAdd(&Hn[(size_t)dstn * DH + lane], acc);   // coalesced 256 B
    }
}

// ---- fused finish + readout (last-block-done ticket) ----------------------
// finish: H = S + Hn/deg (no relu) + per-graph register accumulation with one
// coalesced atomic flush per graph-change (graph_id sorted; R10 profile).
// Last block to finish (agent-scope ticket, once-per-block fences) runs the
// readout with its 256 threads: out_feat = gsum/cnt ; out = of @ Wc + bc.
__global__ __launch_bounds__(256) void finish_readout_kernel(
    const float* __restrict__ S, const float* __restrict__ Hn,
    const int* __restrict__ cnt8, const int* __restrict__ graph_id,
    float* __restrict__ H, float* __restrict__ gsum, float* __restrict__ gcnt,
    const float* __restrict__ Wc, const float* __restrict__ bc,
    float* __restrict__ out, float* __restrict__ out_feat,
    unsigned int* __restrict__ done, int M, int fb) {
    int tid  = threadIdx.x;
    int lane = tid & 63;
    int wv   = tid >> 6;
    {   // ---- finish work (R10/R11-proven) ----
        int wid = blockIdx.x * 4 + wv;
        int nw  = fb * 4;
        int cpw = (M + nw - 1) / nw;
        int n0 = wid * cpw, n1 = min(n0 + cpw, M);
        if (n0 < n1) {
            float acc = 0.f;
            int cnt = 0;
            int cur = graph_id[n0];
            for (int n = n0; n < n1; ++n) {
                int gid = graph_id[n];
                if (gid != cur) {
                    atomicAdd(&gsum[cur * DH + lane], acc);
                    if (lane == 0) atomicAdd(&gcnt[cur], (float)cnt);
                    acc = 0.f; cnt = 0; cur = gid;
                }
                float inv = 1.f / fmaxf((float)deg8(cnt8, n), 1.f);
                size_t o = (size_t)n * DH + lane;
                float val = fmaf(Hn[o], inv, S[o]);
                H[o] = val;
                acc += val;
                ++cnt;
            }
            atomicAdd(&gsum[cur * DH + lane], acc);
            if (lane == 0) atomicAdd(&gcnt[cur], (float)cnt);
        }
    }

    // ---- last-block ticket ----
    __shared__ unsigned int s_ticket;
    __syncthreads();
    if (tid == 0) {
        __threadfence();   // release: publish this block's gsum/gcnt/H
        s_ticket = __hip_atomic_fetch_add(done, 1u, __ATOMIC_ACQ_REL,
                                          __HIP_MEMORY_SCOPE_AGENT);
    }
    __syncthreads();
    if (s_ticket != (unsigned int)(fb - 1)) return;
    if (tid == 0) __threadfence();   // acquire: see all blocks' gsum/gcnt
    __syncthreads();

    // ---- readout by the last block (256 threads, 4 entries each) ----
    __shared__ float ofs[NG][DH];
#pragma unroll
    for (int q = 0; q < 4; ++q) {
        int idx = tid + 256 * q;            // 0..1023 = (g,d)
        int g = idx >> 6, d = idx & 63;
        float of = gsum[idx] / fmaxf(gcnt[g], 1.0f);
        out_feat[idx] = of;
        ofs[g][d] = of;
    }
    __syncthreads();
    if (tid < NG * 2) {
        int gg = tid >> 1, cc = tid & 1;
        float accv = bc[cc];
#pragma unroll 8
        for (int dd = 0; dd < DH; ++dd) accv += ofs[gg][dd] * Wc[dd * 2 + cc];
        out[gg * 2 + cc] = accv;
    }
}

extern "C" void kernel_launch(void* const* d_in, const int* in_sizes, int n_in,
                              void* d_out, int out_size, void* d_ws, size_t ws_size,
                              hipStream_t stream) {
    const float* feat     = (const float*)d_in[0];
    const int*   src      = (const int*)d_in[1];
    const int*   dst      = (const int*)d_in[2];
    const int*   graph_id = (const int*)d_in[3];
    const float* Ws1 = (const float*)d_in[4];
    const float* Wn1 = (const float*)d_in[5];
    const float* b1  = (const float*)d_in[6];
    const float* Ws2 = (const float*)d_in[7];
    const float* Wn2 = (const float*)d_in[8];
    const float* b2  = (const float*)d_in[9];
    const float* Ws3 = (const float*)d_in[10];
    const float* Wn3 = (const float*)d_in[11];
    const float* b3  = (const float*)d_in[12];
    const float* Wc  = (const float*)d_in[13];
    const float* bc  = (const float*)d_in[14];

    const int M  = in_sizes[3];     // 10000 nodes
    const int E  = in_sizes[1];     // 320000 edges
    const int M2 = M * NSB;         // 80000 (dst,bucket) rows
    const int npb8 = (M + NSB - 1) / NSB;   // 1250 (<= MAXNPB)

    float* out      = (float*)d_out;             // 16 x 2
    float* out_feat = out + NG * 2;              // 16 x 64
    float* Hbuf     = out_feat + NG * DH;        // 10000 x 64 (final h)

    // workspace layout (256B-aligned carves)
    char* w = (char*)d_ws;
    size_t off = 0;
    auto carve = [&](size_t bytes) {
        size_t o = off;
        off = (off + bytes + 255) & ~(size_t)255;
        return o;
    };
    int*   cnt8  = (int*)  (w + carve((size_t)M2 * 4));
    float* gsum  = (float*)(w + carve((size_t)NG * DH * 4));
    float* gcnt  = (float*)(w + carve((size_t)NG * 4));
    unsigned int* done = (unsigned int*)(w + carve(4));
    size_t zero_bytes = off;                       // cnt8 + gsum + gcnt + done
    int*   es    = (int*)  (w + carve((size_t)M2 * CAP * 4));   // 10.24 MB
    float* Sbuf  = (float*)(w + carve((size_t)M * DH * 4));
    unsigned short* Pbuf = (unsigned short*)(w + carve((size_t)M * DH * 2));
    float* Hn    = (float*)(w + carve((size_t)M * DH * 4));
    (void)ws_size; (void)n_in; (void)out_size;

    (void)hipMemsetAsync(d_ws, 0, zero_bytes, stream);

    int gb = (M + 63) / 64;          // 157 gemm blocks
    int eb = (E + 255) / 256;        // 1250 build blocks
    int ab = NSB * DTILES;           // 256 agg blocks (1/CU)
    int fb = 160;                    // finish blocks: 640 waves

    // layer 1 (K=256) + CSR build, ONE dispatch (independent outputs)
    gemm1_build_kernel<<<gb + eb, 256, 0, stream>>>(
        feat, Ws1, Wn1, b1, Sbuf, Pbuf, Hn,
        src, dst, cnt8, es, M, E, npb8, gb);
    agg_kernel<<<ab, 1024, 0, stream>>>(Pbuf, cnt8, es, Hn, M, npb8);

    // layer 2 (K=64): X = relu(S1 + Hn1/deg) fused; in-place S/Hn is
    // block-safe (each block reads only its own rows before writing them)
    gemm_dual_kernel<<<gb, 256, 0, stream>>>(
        Sbuf, Ws2, Wn2, b2, Hn, cnt8, Sbuf, Pbuf, Hn, M);
    agg_kernel<<<ab, 1024, 0, stream>>>(Pbuf, cnt8, es, Hn, M, npb8);

    // layer 3 (K=64): X = relu(S2 + Hn2/deg) fused
    gemm_dual_kernel<<<gb, 256, 0, stream>>>(
        Sbuf, Ws3, Wn3, b3, Hn, cnt8, Sbuf, Pbuf, Hn, M);
    agg_kernel<<<ab, 1024, 0, stream>>>(Pbuf, cnt8, es, Hn, M, npb8);

    // finish layer 3 + readout (fused via last-block-done ticket)
    finish_readout_kernel<<<fb, 256, 0, stream>>>(
        Sbuf, Hn, cnt8, graph_id, Hbuf, gsum, gcnt,
        Wc, bc, out, out_feat, done, M, fb);
}

// Round 9
// 232.524 us; speedup vs baseline: 3.7683x; 1.0714x over previous
//
#include <hip/hip_runtime.h>

// ---------------------------------------------------------------------------
// SAGE 3-layer GNN.  (R16 = R15 + split-K wave-group GEMMs)
//   Per layer: S = X@W_self + b (fp32) ; P = X@W_neigh (bf16 row-major)
//              h[i] = act( S[i] + (sum_{j in N_in(i)} P[j]) / max(deg_i,1) )
//
// Evidence log:
//   R0..R5: random row-gather agg ~150us = per-CU gather service wall.
//   R8 FAILED: dim-sliced LDS planes (32x edge visits).
//   R9 WIN: src-bucket LDS slicing + coalesced 256B Hn atomics.
//   R10 WIN: finish via sorted-graph_id register accumulation.
//   R11 WIN: one-pass fixed-cap CSR build. 255.9us.
//   R12/R13/R14: persistent-kernel route FAILED (capture kill; L2-inval
//     spin storm; structurally higher traffic floor). Reverted.
//   R15 WIN (249.1us): build fused into gemm1 dispatch; readout fused into
//     finish via last-block ticket. gemm1_build now visible: 44us,
//     occ 13-15%, VALU 10%, HBM 9% -> latency-bound at 1 wave/SIMD
//     (52KB LDS, 157 blocks -> 1 block/CU x 4 waves).
//   R16 (this round): split-K wave groups. gemm1: 512 thr, grp0 kc{0,64},
//     grp1 kc{128,192}, private LDS (104KB), partial combine via stride-33
//     LDS region (2-way bank = free), grp0 epilogue. gemm2/3: 512 thr,
//     shared stage, kk split 0-31/32-63, same combine. 2 waves/SIMD,
//     half per-wave serial work. Aggs/finish/memset untouched.
//   Predicted: gemm1_build 44 -> 26-32us, VALU 10 -> ~20%, total -> 220-230.
//   If gemm1_build flat -> build atomics dominate; next: ushort es/CAP=24.
// ---------------------------------------------------------------------------

#define DH 64
#define NG 16
#define NSB 8        // src buckets
#define DTILES 32    // dst tiles -> grid 8*32 = 256 agg blocks (1/CU)
#define MAXNPB 1250  // max nodes per bucket (M <= 10000)
#define CAP 32       // edge slots per (dst,bucket) row; Poisson(4) tail ~1e-19
#define TILE_F 4352  // 64*68 floats per LDS tile

__device__ __forceinline__ unsigned short f2bf(float f) {
    unsigned int u = __float_as_uint(f);
    unsigned int r = (u + 0x7FFFu + ((u >> 16) & 1u)) >> 16;   // RNE
    return (unsigned short)r;
}
__device__ __forceinline__ float bfu(unsigned short v) {
    return __uint_as_float(((unsigned int)v) << 16);
}
__device__ __forceinline__ int deg8(const int* __restrict__ cnt8, int n) {
    const int4* cp = reinterpret_cast<const int4*>(&cnt8[n * NSB]);
    int4 c0 = cp[0], c1 = cp[1];
    return c0.x + c0.y + c0.z + c0.w + c1.x + c1.y + c1.z + c1.w;
}

// ---- fused: layer-1 dual GEMM (blocks [0,gb)) + CSR build ([gb,gb+eb)) ----
// 512 threads. gemm: split-K wave groups — grp0 kc{0,64}, grp1 kc{128,192},
// each group stages into its own LDS tile-set; grp1 writes fp32 partials to
// its (dead) LDS region stride-33; grp0 adds + epilogue (S,P,Hn=0).
// build: one edge per thread, p=atomicAdd(cnt8[key]); es[key*CAP+p]=src.
__global__ __launch_bounds__(512) void gemm1_build_kernel(
    const float* __restrict__ X, const float* __restrict__ Ws_g,
    const float* __restrict__ Wn_g, const float* __restrict__ bias,
    float* __restrict__ S, unsigned short* __restrict__ P,
    float* __restrict__ Hn_out,
    const int* __restrict__ src, const int* __restrict__ dst,
    int* __restrict__ cnt8, int* __restrict__ es,
    int M, int E, int npb8, int gb) {
    constexpr int K = 256;
    int tid = threadIdx.x;

    if ((int)blockIdx.x >= gb) {          // ---- build part ----
        int i = ((int)blockIdx.x - gb) * 512 + tid;
        if (i < E) {
            int s = src[i];
            int k = dst[i] * NSB + s / npb8;
            int p = atomicAdd(&cnt8[k], 1);
            if (p < CAP) es[(size_t)k * CAP + p] = s;   // clamp: memory-safe
        }
        return;
    }

    // ---- gemm part: split-K over 2 wave groups ----
    __shared__ float smem[6 * TILE_F];    // grp0: Xs,Ws,Wn ; grp1: Xs,Ws,Wn
    const int grp = tid >> 8;             // 0: waves 0-3, 1: waves 4-7
    const int t   = tid & 255;
    const int cx = t & 15;
    const int ry = t >> 4;
    float* Xs  = smem + grp * 3 * TILE_F;
    float* Wsm = Xs + TILE_F;
    float* Wnm = Wsm + TILE_F;
    const int row0 = blockIdx.x * 64;
    float acc_s[4][4] = {{0.f}};
    float acc_n[4][4] = {{0.f}};

    for (int st = 0; st < 2; ++st) {
        const int kc = grp * 128 + st * 64;
#pragma unroll
        for (int it = 0; it < 4; ++it) {
            int q = t + 256 * it;         // 0..1023
            int row = q >> 4;
            int k4 = (q & 15) * 4;
            float4 xv = make_float4(0.f, 0.f, 0.f, 0.f);
            int gr = row0 + row;
            if (gr < M)
                xv = *reinterpret_cast<const float4*>(&X[(size_t)gr * K + kc + k4]);
            *reinterpret_cast<float4*>(&Xs[row * 68 + k4]) = xv;
            *reinterpret_cast<float4*>(&Wsm[row * 68 + k4]) =
                *reinterpret_cast<const float4*>(&Ws_g[(size_t)(kc + row) * 64 + k4]);
            *reinterpret_cast<float4*>(&Wnm[row * 68 + k4]) =
                *reinterpret_cast<const float4*>(&Wn_g[(size_t)(kc + row) * 64 + k4]);
        }
        __syncthreads();
#pragma unroll 4
        for (int kk = 0; kk < 64; ++kk) {
            float av[4], bs[4], bn[4];
#pragma unroll
            for (int j = 0; j < 4; ++j) av[j] = Xs[(ry * 4 + j) * 68 + kk];
#pragma unroll
            for (int i = 0; i < 4; ++i) {
                bs[i] = Wsm[kk * 68 + cx + 16 * i];
                bn[i] = Wnm[kk * 68 + cx + 16 * i];
            }
#pragma unroll
            for (int j = 0; j < 4; ++j)
#pragma unroll
                for (int i = 0; i < 4; ++i) {
                    acc_s[j][i] += av[j] * bs[i];
                    acc_n[j][i] += av[j] * bn[i];
                }
        }
        __syncthreads();
    }

    // combine: grp1 -> its own (dead) LDS region, stride 33 (bank-free)
    float* flat = smem + 3 * TILE_F;
    if (grp == 1) {
        int o = t * 33;
#pragma unroll
        for (int j = 0; j < 4; ++j)
#pragma unroll
            for (int i = 0; i < 4; ++i) {
                flat[o + j * 4 + i]      = acc_s[j][i];
                flat[o + 16 + j * 4 + i] = acc_n[j][i];
            }
    }
    __syncthreads();
    if (grp == 0) {
        int o = t * 33;
#pragma unroll
        for (int j = 0; j < 4; ++j)
#pragma unroll
            for (int i = 0; i < 4; ++i) {
                acc_s[j][i] += flat[o + j * 4 + i];
                acc_n[j][i] += flat[o + 16 + j * 4 + i];
            }
#pragma unroll
        for (int j = 0; j < 4; ++j) {
            int r = row0 + ry * 4 + j;
            if (r < M) {
#pragma unroll
                for (int i = 0; i < 4; ++i) {
                    int col = cx + 16 * i;
                    S[(size_t)r * DH + col] = acc_s[j][i] + bias[col];
                    P[(size_t)r * DH + col] = f2bf(acc_n[j][i]);
                    Hn_out[(size_t)r * DH + col] = 0.f;
                }
            }
        }
    }
}

// ---- dual GEMM layers 2/3 (K=64): X = relu(S + Hn/deg) fused on load ------
// 512 threads: all stage the single 64x64 tile-set once; grp0 computes
// kk 0-31, grp1 kk 32-63; combine via stride-33 LDS reuse; grp0 epilogue.
__global__ __launch_bounds__(512) void gemm_dual_kernel(
    const float* __restrict__ X, const float* __restrict__ Ws_g,
    const float* __restrict__ Wn_g, const float* __restrict__ bias,
    const float* __restrict__ Hn_in, const int* __restrict__ cnt8,
    float* __restrict__ S, unsigned short* __restrict__ P,
    float* __restrict__ Hn_out, int M) {
    constexpr int K = 64;
    __shared__ float smem[3 * TILE_F];    // Xs, Ws, Wn (combine reuses base)
    int tid = threadIdx.x;
    const int grp = tid >> 8;
    const int t   = tid & 255;
    const int cx = t & 15;
    const int ry = t >> 4;
    float* Xs  = smem;
    float* Wsm = smem + TILE_F;
    float* Wnm = smem + 2 * TILE_F;
    const int row0 = blockIdx.x * 64;
    float acc_s[4][4] = {{0.f}};
    float acc_n[4][4] = {{0.f}};

    {   // stage by all 512 threads (2 passes cover 64 rows x 16 k4-groups)
#pragma unroll
        for (int it = 0; it < 2; ++it) {
            int q = tid + 512 * it;       // 0..1023
            int row = q >> 4;
            int k4 = (q & 15) * 4;
            float4 xv = make_float4(0.f, 0.f, 0.f, 0.f);
            int gr = row0 + row;
            if (gr < M) {
                xv = *reinterpret_cast<const float4*>(&X[(size_t)gr * K + k4]);
                float4 hv = *reinterpret_cast<const float4*>(&Hn_in[(size_t)gr * DH + k4]);
                float inv = 1.f / fmaxf((float)deg8(cnt8, gr), 1.f);
                xv.x = fmaxf(fmaf(hv.x, inv, xv.x), 0.f);
                xv.y = fmaxf(fmaf(hv.y, inv, xv.y), 0.f);
                xv.z = fmaxf(fmaf(hv.z, inv, xv.z), 0.f);
                xv.w = fmaxf(fmaf(hv.w, inv, xv.w), 0.f);
            }
            *reinterpret_cast<float4*>(&Xs[row * 68 + k4]) = xv;
            *reinterpret_cast<float4*>(&Wsm[row * 68 + k4]) =
                *reinterpret_cast<const float4*>(&Ws_g[(size_t)row * 64 + k4]);
            *reinterpret_cast<float4*>(&Wnm[row * 68 + k4]) =
                *reinterpret_cast<const float4*>(&Wn_g[(size_t)row * 64 + k4]);
        }
        __syncthreads();
        const int kk0 = grp * 32;
#pragma unroll 4
        for (int kk = kk0; kk < kk0 + 32; ++kk) {
            float av[4], bs[4], bn[4];
#pragma unroll
            for (int j = 0; j < 4; ++j) av[j] = Xs[(ry * 4 + j) * 68 + kk];
#pragma unroll
            for (int i = 0; i < 4; ++i) {
                bs[i] = Wsm[kk * 68 + cx + 16 * i];
                bn[i] = Wnm[kk * 68 + cx + 16 * i];
            }
#pragma unroll
            for (int j = 0; j < 4; ++j)
#pragma unroll
                for (int i = 0; i < 4; ++i) {
                    acc_s[j][i] += av[j] * bs[i];
                    acc_n[j][i] += av[j] * bn[i];
                }
        }
        __syncthreads();   // all reads of Xs/Ws/Wn done -> safe to reuse
    }

    // combine: grp1 partials into reused smem base, stride 33
    if (grp == 1) {
        int o = t * 33;
#pragma unroll
        for (int j = 0; j < 4; ++j)
#pragma unroll
            for (int i = 0; i < 4; ++i) {
                smem[o + j * 4 + i]      = acc_s[j][i];
                smem[o + 16 + j * 4 + i] = acc_n[j][i];
            }
    }
    __syncthreads();
    if (grp == 0) {
        int o = t * 33;
#pragma unroll
        for (int j = 0; j < 4; ++j)
#pragma unroll
            for (int i = 0; i < 4; ++i) {
                acc_s[j][i] += smem[o + j * 4 + i];
                acc_n[j][i] += smem[o + 16 + j * 4 + i];
            }
#pragma unroll
        for (int j = 0; j < 4; ++j) {
            int r = row0 + ry * 4 + j;
            if (r < M) {
#pragma unroll
                for (int i = 0; i < 4; ++i) {
                    int col = cx + 16 * i;
                    S[(size_t)r * DH + col] = acc_s[j][i] + bias[col];
                    P[(size_t)r * DH + col] = f2bf(acc_n[j][i]);
                    Hn_out[(size_t)r * DH + col] = 0.f;
                }
            }
        }
    }
}

// ---- aggregation: src-bucket LDS slice, wave-per-(dst,bucket) row ----------
// grid = NSB * DTILES blocks x 1024 threads. LDS = 1250*64 bf16 = 160,000 B.
__global__ __launch_bounds__(1024) void agg_kernel(
    const unsigned short* __restrict__ P, const int* __restrict__ cnt8,
    const int* __restrict__ es, float* __restrict__ Hn, int M, int npb8) {
    __shared__ __align__(16) unsigned short sP[MAXNPB * DH];
    int tid = threadIdx.x;
    int sb    = blockIdx.x & (NSB - 1);
    int dtile = blockIdx.x >> 3;
    int s0 = sb * npb8;
    int snodes = min(npb8, M - s0);

    // stage this bucket's P slice (coalesced uint4)
    {
        const uint4* gp = reinterpret_cast<const uint4*>(P + (size_t)s0 * DH);
        int cnt = snodes * 8;   // 128 B/node / 16 B
        for (int j = tid; j < cnt; j += 1024)
            *reinterpret_cast<uint4*>(&sP[j * 8]) = gp[j];
    }
    __syncthreads();

    int lane = tid & 63, wid = tid >> 6;
    int dpb  = (M + DTILES - 1) / DTILES;
    int d0t  = dtile * dpb;
    int dend = min(d0t + dpb, M);

    for (int dstn = d0t + wid; dstn < dend; dstn += 16) {
        int key = dstn * NSB + sb;
        int cnt = min(cnt8[key], CAP);
        if (cnt == 0) continue;
        size_t base = (size_t)key * CAP;
        float acc = 0.f;
        int cmax = cnt - 1;
        for (int e = 0; e < cnt; e += 4) {
            int i0 = es[base + min(e + 0, cmax)] - s0;
            int i1 = es[base + min(e + 1, cmax)] - s0;
            int i2 = es[base + min(e + 2, cmax)] - s0;
            int i3 = es[base + min(e + 3, cmax)] - s0;
            float m1 = (e + 1 < cnt) ? 1.f : 0.f;
            float m2 = (e + 2 < cnt) ? 1.f : 0.f;
            float m3 = (e + 3 < cnt) ? 1.f : 0.f;
            float f0 = bfu(sP[(size_t)i0 * DH + lane]);
            float f1 = bfu(sP[(size_t)i1 * DH + lane]);
            float f2 = bfu(sP[(size_t)i2 * DH + lane]);
            float f3 = bfu(sP[(size_t)i3 * DH + lane]);
            acc += f0;                       // e+0 always valid in-loop
            acc = fmaf(m1, f1, acc);
            acc = fmaf(m2, f2, acc);
            acc = fmaf(m3, f3, acc);
        }
        atomicAdd(&Hn[(size_t)dstn * DH + lane], acc);   // coalesced 256 B
    }
}

// ---- fused finish + readout (last-block-done ticket) ----------------------
__global__ __launch_bounds__(256) void finish_readout_kernel(
    const float* __restrict__ S, const float* __restrict__ Hn,
    const int* __restrict__ cnt8, const int* __restrict__ graph_id,
    float* __restrict__ H, float* __restrict__ gsum, float* __restrict__ gcnt,
    const float* __restrict__ Wc, const float* __restrict__ bc,
    float* __restrict__ out, float* __restrict__ out_feat,
    unsigned int* __restrict__ done, int M, int fb) {
    int tid  = threadIdx.x;
    int lane = tid & 63;
    int wv   = tid >> 6;
    {   // ---- finish work (R10/R11-proven) ----
        int wid = blockIdx.x * 4 + wv;
        int nw  = fb * 4;
        int cpw = (M + nw - 1) / nw;
        int n0 = wid * cpw, n1 = min(n0 + cpw, M);
        if (n0 < n1) {
            float acc = 0.f;
            int cnt = 0;
            int cur = graph_id[n0];
            for (int n = n0; n < n1; ++n) {
                int gid = graph_id[n];
                if (gid != cur) {
                    atomicAdd(&gsum[cur * DH + lane], acc);
                    if (lane == 0) atomicAdd(&gcnt[cur], (float)cnt);
                    acc = 0.f; cnt = 0; cur = gid;
                }
                float inv = 1.f / fmaxf((float)deg8(cnt8, n), 1.f);
                size_t o = (size_t)n * DH + lane;
                float val = fmaf(Hn[o], inv, S[o]);
                H[o] = val;
                acc += val;
                ++cnt;
            }
            atomicAdd(&gsum[cur * DH + lane], acc);
            if (lane == 0) atomicAdd(&gcnt[cur], (float)cnt);
        }
    }

    // ---- last-block ticket ----
    __shared__ unsigned int s_ticket;
    __syncthreads();
    if (tid == 0) {
        __threadfence();   // release: publish this block's gsum/gcnt/H
        s_ticket = __hip_atomic_fetch_add(done, 1u, __ATOMIC_ACQ_REL,
                                          __HIP_MEMORY_SCOPE_AGENT);
    }
    __syncthreads();
    if (s_ticket != (unsigned int)(fb - 1)) return;
    if (tid == 0) __threadfence();   // acquire: see all blocks' gsum/gcnt
    __syncthreads();

    // ---- readout by the last block (256 threads, 4 entries each) ----
    __shared__ float ofs[NG][DH];
#pragma unroll
    for (int q = 0; q < 4; ++q) {
        int idx = tid + 256 * q;            // 0..1023 = (g,d)
        int g = idx >> 6, d = idx & 63;
        float of = gsum[idx] / fmaxf(gcnt[g], 1.0f);
        out_feat[idx] = of;
        ofs[g][d] = of;
    }
    __syncthreads();
    if (tid < NG * 2) {
        int gg = tid >> 1, cc = tid & 1;
        float accv = bc[cc];
#pragma unroll 8
        for (int dd = 0; dd < DH; ++dd) accv += ofs[gg][dd] * Wc[dd * 2 + cc];
        out[gg * 2 + cc] = accv;
    }
}

extern "C" void kernel_launch(void* const* d_in, const int* in_sizes, int n_in,
                              void* d_out, int out_size, void* d_ws, size_t ws_size,
                              hipStream_t stream) {
    const float* feat     = (const float*)d_in[0];
    const int*   src      = (const int*)d_in[1];
    const int*   dst      = (const int*)d_in[2];
    const int*   graph_id = (const int*)d_in[3];
    const float* Ws1 = (const float*)d_in[4];
    const float* Wn1 = (const float*)d_in[5];
    const float* b1  = (const float*)d_in[6];
    const float* Ws2 = (const float*)d_in[7];
    const float* Wn2 = (const float*)d_in[8];
    const float* b2  = (const float*)d_in[9];
    const float* Ws3 = (const float*)d_in[10];
    const float* Wn3 = (const float*)d_in[11];
    const float* b3  = (const float*)d_in[12];
    const float* Wc  = (const float*)d_in[13];
    const float* bc  = (const float*)d_in[14];

    const int M  = in_sizes[3];     // 10000 nodes
    const int E  = in_sizes[1];     // 320000 edges
    const int M2 = M * NSB;         // 80000 (dst,bucket) rows
    const int npb8 = (M + NSB - 1) / NSB;   // 1250 (<= MAXNPB)

    float* out      = (float*)d_out;             // 16 x 2
    float* out_feat = out + NG * 2;              // 16 x 64
    float* Hbuf     = out_feat + NG * DH;        // 10000 x 64 (final h)

    // workspace layout (256B-aligned carves)
    char* w = (char*)d_ws;
    size_t off = 0;
    auto carve = [&](size_t bytes) {
        size_t o = off;
        off = (off + bytes + 255) & ~(size_t)255;
        return o;
    };
    int*   cnt8  = (int*)  (w + carve((size_t)M2 * 4));
    float* gsum  = (float*)(w + carve((size_t)NG * DH * 4));
    float* gcnt  = (float*)(w + carve((size_t)NG * 4));
    unsigned int* done = (unsigned int*)(w + carve(4));
    size_t zero_bytes = off;                       // cnt8 + gsum + gcnt + done
    int*   es    = (int*)  (w + carve((size_t)M2 * CAP * 4));   // 10.24 MB
    float* Sbuf  = (float*)(w + carve((size_t)M * DH * 4));
    unsigned short* Pbuf = (unsigned short*)(w + carve((size_t)M * DH * 2));
    float* Hn    = (float*)(w + carve((size_t)M * DH * 4));
    (void)ws_size; (void)n_in; (void)out_size;

    (void)hipMemsetAsync(d_ws, 0, zero_bytes, stream);

    int gb = (M + 63) / 64;          // 157 gemm blocks
    int eb = (E + 511) / 512;        // 625 build blocks (512 thr)
    int ab = NSB * DTILES;           // 256 agg blocks (1/CU)
    int fb = 160;                    // finish blocks: 640 waves

    // layer 1 (K=256, split-K) + CSR build, ONE dispatch
    gemm1_build_kernel<<<gb + eb, 512, 0, stream>>>(
        feat, Ws1, Wn1, b1, Sbuf, Pbuf, Hn,
        src, dst, cnt8, es, M, E, npb8, gb);
    agg_kernel<<<ab, 1024, 0, stream>>>(Pbuf, cnt8, es, Hn, M, npb8);

    // layer 2 (K=64, split-kk): X = relu(S1 + Hn1/deg) fused; in-place S/Hn
    // is block-safe (each block reads only its own rows before writing them)
    gemm_dual_kernel<<<gb, 512, 0, stream>>>(
        Sbuf, Ws2, Wn2, b2, Hn, cnt8, Sbuf, Pbuf, Hn, M);
    agg_kernel<<<ab, 1024, 0, stream>>>(Pbuf, cnt8, es, Hn, M, npb8);

    // layer 3 (K=64, split-kk): X = relu(S2 + Hn2/deg) fused
    gemm_dual_kernel<<<gb, 512, 0, stream>>>(
        Sbuf, Ws3, Wn3, b3, Hn, cnt8, Sbuf, Pbuf, Hn, M);
    agg_kernel<<<ab, 1024, 0, stream>>>(Pbuf, cnt8, es, Hn, M, npb8);

    // finish layer 3 + readout (fused via last-block-done ticket)
    finish_readout_kernel<<<fb, 256, 0, stream>>>(
        Sbuf, Hn, cnt8, graph_id, Hbuf, gsum, gcnt,
        Wc, bc, out, out_feat, done, M, fb);
}